// Round 13
// baseline (180.733 us; speedup 1.0000x reference)
//
#include <hip/hip_runtime.h>
#include <hip/hip_bf16.h>
#include <math.h>

// Problem constants
#define BATCH 2
#define SEQ   2048
#define DMODEL 1024
#define NHEADS 16
#define DHEAD 64
#define MROWS (BATCH*SEQ)   // 4096

typedef __attribute__((ext_vector_type(8))) short bf16x8;
typedef __attribute__((ext_vector_type(4))) short bf16x4;
typedef __attribute__((ext_vector_type(4))) float f32x4;

__device__ __forceinline__ short f2bf(float f) {   // RNE float->bf16
    union { float f; unsigned u; } c; c.f = f;
    unsigned r = (c.u + 0x7fffu + ((c.u >> 16) & 1u)) >> 16;
    return (short)r;
}
__device__ __forceinline__ float bf2f(short h) {
    union { unsigned u; float f; } c; c.u = ((unsigned)(unsigned short)h) << 16;
    return c.f;
}

__device__ __forceinline__ void async_ld16(const void* g, void* l) {
    __builtin_amdgcn_global_load_lds(
        (const __attribute__((address_space(1))) unsigned*)g,
        (__attribute__((address_space(3))) unsigned*)l, 16, 0, 0);
}

// gfx950 cross-lane pair swaps (both outputs usable; in-place on 2 VGPRs)
__device__ __forceinline__ void pl32swap(unsigned &a, unsigned &b) {
    asm("v_permlane32_swap_b32 %0, %1" : "+v"(a), "+v"(b));
}
__device__ __forceinline__ void pl16swap(unsigned &a, unsigned &b) {
    asm("v_permlane16_swap_b32 %0, %1" : "+v"(a), "+v"(b));
}
__device__ __forceinline__ bf16x8 mk8(unsigned a, unsigned b, unsigned c, unsigned d) {
    union { unsigned u[4]; bf16x8 h; } t;
    t.u[0] = a; t.u[1] = b; t.u[2] = c; t.u[3] = d; return t.h;
}

// ---------------- fused prep: convert x -> bf16 AND transpose 4 weights ----------------
__global__ __launch_bounds__(256) void prep(
    const float* __restrict__ x, short* __restrict__ xhi,
    const float* __restrict__ W0, const float* __restrict__ W1,
    const float* __restrict__ W2, const float* __restrict__ W3,
    short* __restrict__ oqkv, short* __restrict__ oo)
{
    __shared__ float T[64][65];
    const int tid = threadIdx.x;
    if (blockIdx.x < 2048) {
        const int i = blockIdx.x * 256 + tid;
        const float4* p = (const float4*)x + (size_t)i * 2;
        float4 a = p[0], b = p[1];
        float v[8] = {a.x, a.y, a.z, a.w, b.x, b.y, b.z, b.w};
        bf16x8 H;
        #pragma unroll
        for (int j = 0; j < 8; ++j) H[j] = f2bf(v[j]);
        *((bf16x8*)xhi + i) = H;
        return;
    }
    const int bi = blockIdx.x - 2048;
    const int z = bi >> 8;
    const int t = bi & 255;
    const float* W = (z == 0) ? W0 : (z == 1) ? W1 : (z == 2) ? W2 : W3;
    short* out = (z < 3) ? (oqkv + (size_t)z * 1024 * 1024) : oo;
    const int n0 = (t & 15) * 64, k0 = (t >> 4) * 64;
    #pragma unroll
    for (int i = 0; i < 16; ++i) {
        const int idx = tid + i * 256;
        const int r = idx >> 6, c = idx & 63;
        T[r][c] = W[(size_t)(k0 + r) * DMODEL + n0 + c];
    }
    __syncthreads();
    #pragma unroll
    for (int i = 0; i < 4; ++i) {
        const int idx = tid + i * 256;
        const int r = idx >> 4, g = idx & 15;
        bf16x4 H;
        #pragma unroll
        for (int j = 0; j < 4; ++j)
            H[j] = f2bf(T[g * 4 + j][r]);
        *(bf16x4*)(out + (size_t)(n0 + r) * DMODEL + k0 + g * 4) = H;
    }
}

// ---------------- QKV GEMM v3: 128x128 tile + XCD swizzle, 768 blocks (3/CU) ----------------
__global__ __launch_bounds__(256, 3) void qkv_gemm(
    const short* __restrict__ Ahi, const short* __restrict__ Bthi,
    const float* __restrict__ b0, const float* __restrict__ b1, const float* __restrict__ b2,
    short* __restrict__ oqh, short* __restrict__ okh, short* __restrict__ ovh,
    float qscale)
{
    __shared__ short Ah[128 * 64], Bh[128 * 64];   // 16 KB + 16 KB

    const int tid  = threadIdx.x;
    const int lane = tid & 63;
    const int w    = tid >> 6;
    const int quad = lane >> 4;
    const int l15  = lane & 15;
    const int wr   = w >> 1, wc = w & 1;
    // XCD-aware swizzle: dispatch id -> contiguous logical chunk per XCD
    const int bid = blockIdx.y * 24 + blockIdx.x;      // 768 blocks
    const int swz = (bid & 7) * 96 + (bid >> 3);       // bijective (768%8==0)
    const int m0   = (swz / 24) * 128;
    const int n0   = (swz % 24) * 128;
    const int K    = DMODEL;

    f32x4 acc[4][4] = {};

    for (int k0 = 0; k0 < K; k0 += 64) {
        __syncthreads();
        // 2048 chunks (A:1024, B:1024); 8 wave-uniform calls/thread
        #pragma unroll
        for (int j = 0; j < 8; ++j) {
            const int base = w * 512 + j * 64;   // waves 0-1 -> A, 2-3 -> B (uniform)
            const int c = base + lane;
            if (base < 1024) {
                const int row = c >> 3, pos = (c & 7) ^ (row & 7);
                async_ld16(Ahi + (size_t)(m0 + row) * K + k0 + pos * 8, Ah + base * 8);
            } else {
                const int cb = c - 1024;
                const int row = cb >> 3, pos = (cb & 7) ^ (row & 7);
                async_ld16(Bthi + (size_t)(n0 + row) * K + k0 + pos * 8, Bh + (base - 1024) * 8);
            }
        }
        __syncthreads();

        #pragma unroll
        for (int s = 0; s < 2; ++s) {
            bf16x8 afh[4], bfh[4];
            #pragma unroll
            for (int mi = 0; mi < 4; ++mi) {
                const int row = wr * 64 + mi * 16 + l15;
                const int pos = (s * 4 + quad) ^ (row & 7);
                afh[mi] = *(const bf16x8*)(Ah + row * 64 + pos * 8);
            }
            #pragma unroll
            for (int ni = 0; ni < 4; ++ni) {
                const int row = wc * 64 + ni * 16 + l15;
                const int pos = (s * 4 + quad) ^ (row & 7);
                bfh[ni] = *(const bf16x8*)(Bh + row * 64 + pos * 8);
            }
            #pragma unroll
            for (int mi = 0; mi < 4; ++mi)
                #pragma unroll
                for (int ni = 0; ni < 4; ++ni)
                    acc[mi][ni] = __builtin_amdgcn_mfma_f32_16x16x32_bf16(
                        afh[mi], bfh[ni], acc[mi][ni], 0, 0, 0);
        }
    }

    const int nbase = n0 + wc * 64;              // one head per wave
    const int which = nbase >> 10;               // 0=q, 1=k, 2=v (wave-uniform)
    const int hh = (nbase & 1023) >> 6;
    const int mb = m0 + wr * 64;
    const int b = mb >> 11, sbase = mb & (SEQ - 1);
    __syncthreads();   // all waves done reading Ah/Bh; reuse as scratch
    short* scr = (w < 2) ? (Ah + w * 4096) : (Bh + (w - 2) * 4096);  // 8 KB/wave

    if (which < 2) {
        const float* bias = which ? b1 : b0;
        short* dstp = which ? okh : oqh;
        const float scl = which ? 1.0f : qscale;
        #pragma unroll
        for (int mi = 0; mi < 4; ++mi)
            #pragma unroll
            for (int ni = 0; ni < 4; ++ni)
                #pragma unroll
                for (int r = 0; r < 4; ++r) {
                    const int sloc = mi * 16 + quad * 4 + r;
                    const int dloc = ni * 16 + l15;
                    const int nn = (nbase + ni * 16 + l15) & 1023;
                    scr[sloc * 64 + (((dloc >> 3) ^ (sloc & 7)) * 8) + (dloc & 7)] =
                        f2bf((acc[mi][ni][r] + bias[nn]) * scl);
                }
        #pragma unroll
        for (int i = 0; i < 8; ++i) {
            const int sloc = i * 8 + (lane >> 3);
            const int cph = (lane & 7) ^ (sloc & 7);
            bf16x8 row = *(const bf16x8*)(scr + sloc * 64 + cph * 8);
            const int dloc = (lane & 7) * 8;
            *(bf16x8*)(dstp + ((size_t)(b * NHEADS + hh) * SEQ + sbase + sloc) * DHEAD + dloc) = row;
        }
    } else {
        #pragma unroll
        for (int mi = 0; mi < 4; ++mi)
            #pragma unroll
            for (int ni = 0; ni < 4; ++ni)
                #pragma unroll
                for (int r = 0; r < 4; ++r) {
                    const int sloc = mi * 16 + quad * 4 + r;
                    const int dloc = ni * 16 + l15;
                    const int nn = (nbase + ni * 16 + l15) & 1023;
                    scr[dloc * 64 + (((sloc >> 3) ^ (dloc & 7)) * 8) + (sloc & 7)] =
                        f2bf(acc[mi][ni][r] + b2[nn]);
                }
        #pragma unroll
        for (int i = 0; i < 8; ++i) {
            const int dloc = i * 8 + (lane >> 3);
            const int cph = (lane & 7) ^ (dloc & 7);
            bf16x8 row = *(const bf16x8*)(scr + dloc * 64 + cph * 8);
            const int sg = sbase + (lane & 7) * 8;
            *(bf16x8*)(ovh + ((size_t)(b * NHEADS + hh) * DHEAD + dloc) * SEQ + sg) = row;
        }
    }
}

// ---------------- O-proj GEMM v4: REVERT to 64x64 tile, grid (16,64)=1024 (4/CU) ----------------
// R13 hypothesis: R2's ogemm change (64x64@4/CU -> 64x128@2/CU) was a hidden
// regression masked by the simultaneous qkv gain -- the session ledger says
// TLP (blocks/CU) beats instruction-ratio at K=1024. This is R0's passing
// kernel byte-for-byte (8:8 ratio, 16 KB LDS, 4 blocks/CU).
__global__ __launch_bounds__(256) void ogemm(
    const short* __restrict__ Ahi, const short* __restrict__ Bthi,
    const float* __restrict__ b0, float* __restrict__ outf)
{
    __shared__ short Ah[64 * 64], Bh[64 * 64];   // 8 KB + 8 KB

    const int tid  = threadIdx.x;
    const int lane = tid & 63;
    const int w    = tid >> 6;
    const int quad = lane >> 4;
    const int l15  = lane & 15;
    const int wr   = w >> 1, wc = w & 1;
    const int m0   = blockIdx.y * 64;
    const int n0   = blockIdx.x * 64;
    const int K    = DMODEL;

    f32x4 acc[2][2] = {};

    for (int k0 = 0; k0 < K; k0 += 64) {
        __syncthreads();
        // 1024 chunks (A:512, B:512); 4 wave-uniform calls/wave
        #pragma unroll
        for (int j = 0; j < 4; ++j) {
            const int base = w * 256 + j * 64;   // w<2 -> A, w>=2 -> B (uniform)
            const int c = base + lane;
            if (base < 512) {
                const int row = c >> 3, pos = (c & 7) ^ (row & 7);
                async_ld16(Ahi + (size_t)(m0 + row) * K + k0 + pos * 8, Ah + base * 8);
            } else {
                const int cb = c - 512;
                const int row = cb >> 3, pos = (cb & 7) ^ (row & 7);
                async_ld16(Bthi + (size_t)(n0 + row) * K + k0 + pos * 8, Bh + (base - 512) * 8);
            }
        }
        __syncthreads();

        #pragma unroll
        for (int s = 0; s < 2; ++s) {
            bf16x8 afh[2], bfh[2];
            #pragma unroll
            for (int mi = 0; mi < 2; ++mi) {
                const int row = wr * 32 + mi * 16 + l15;
                const int pos = (s * 4 + quad) ^ (row & 7);
                afh[mi] = *(const bf16x8*)(Ah + row * 64 + pos * 8);
            }
            #pragma unroll
            for (int ni = 0; ni < 2; ++ni) {
                const int row = wc * 32 + ni * 16 + l15;
                const int pos = (s * 4 + quad) ^ (row & 7);
                bfh[ni] = *(const bf16x8*)(Bh + row * 64 + pos * 8);
            }
            #pragma unroll
            for (int mi = 0; mi < 2; ++mi)
                #pragma unroll
                for (int ni = 0; ni < 2; ++ni)
                    acc[mi][ni] = __builtin_amdgcn_mfma_f32_16x16x32_bf16(
                        afh[mi], bfh[ni], acc[mi][ni], 0, 0, 0);
        }
    }

    #pragma unroll
    for (int mi = 0; mi < 2; ++mi)
        #pragma unroll
        for (int ni = 0; ni < 2; ++ni)
            #pragma unroll
            for (int r = 0; r < 4; ++r) {
                const int m = m0 + wr * 32 + mi * 16 + quad * 4 + r;
                const int nn = n0 + wc * 32 + ni * 16 + l15;
                outf[(size_t)m * DMODEL + nn] = acc[mi][ni][r] + b0[nn];
            }
}

// ---------------- MFMA flash attention v19 (FROZEN): 8-wave, two-barrier loop, sk=1 ----------------
__global__ __launch_bounds__(512) void attn_mfma(
    const short* __restrict__ Qh_g, const short* __restrict__ Kh_g,
    const short* __restrict__ Vth_g,
    short* __restrict__ aoh)
{
    __shared__ short Ksh[4096];          // [key][d] swizzled, 8 KB
    __shared__ short Vsh[4096];          // [d][s] swizzled, 8 KB

    const int tid  = threadIdx.x;
    const int lane = tid & 63;
    const int w    = tid >> 6;           // 0..7
    const int quad = lane >> 4;
    const int l15  = lane & 15;

    const int bh    = blockIdx.x & 31;        // XCD-local head
    const int qtile = blockIdx.x >> 5;        // 0..7
    const int q0    = qtile * 256 + w * 32;
    const size_t kvb = (size_t)bh * SEQ * DHEAD;

    bf16x8 ones;
    #pragma unroll
    for (int j = 0; j < 8; ++j) ones[j] = (short)0x3f80;   // bf16 1.0

    bf16x8 qA[2], qB[2];
    {
        const size_t qrA = kvb + (size_t)(q0 + l15) * DHEAD;
        const size_t qrB = kvb + (size_t)(q0 + 16 + l15) * DHEAD;
        qA[0] = *(const bf16x8*)(Qh_g + qrA + quad * 8);
        qA[1] = *(const bf16x8*)(Qh_g + qrA + 32 + quad * 8);
        qB[0] = *(const bf16x8*)(Qh_g + qrB + quad * 8);
        qB[1] = *(const bf16x8*)(Qh_g + qrB + 32 + quad * 8);
    }

    const bool stager = (w < 4);
    const bool isv = (w >= 2) && stager;
    short* dst = isv ? Vsh : Ksh;
    // per-j pre-swizzled global offsets + linear LDS write addresses (stagers only)
    int goff[4]; short* ldst[4];
    #pragma unroll
    for (int j = 0; j < 4; ++j) {
        const int c = (w & 1) * 256 + j * 64 + lane;
        const int row = c >> 3, pos = (c & 7) ^ (row & 7);
        goff[j] = isv ? (row * SEQ + pos * 8) : (row * DHEAD + pos * 8);
        ldst[j] = dst + (size_t)c * 8;
    }

    const int kb1 = SEQ;                                   // 32 iters of 64 keys
    const int step = isv ? 64 : 64 * DHEAD;
    const short* src = isv ? (Vth_g + kvb) : (Kh_g + kvb);

    f32x4 oA[4] = {}, oB[4] = {};
    f32x4 lAv = {}, lBv = {};

    // prologue: stagers load first tile into registers
    bf16x8 stg[4];
    if (stager) {
        #pragma unroll
        for (int j = 0; j < 4; ++j) stg[j] = *(const bf16x8*)(src + goff[j]);
        src += step;
    }

    for (int kb = 0; kb < kb1; kb += 64) {
        __syncthreads();                 // A: all waves done reading prev tile
        if (stager) {
            #pragma unroll
            for (int j = 0; j < 4; ++j) *(bf16x8*)ldst[j] = stg[j];
        }
        __syncthreads();                 // B: writes visible to all waves
        if (stager && kb + 64 < kb1) {   // prefetch next tile; flies under compute
            #pragma unroll
            for (int j = 0; j < 4; ++j) stg[j] = *(const bf16x8*)(src + goff[j]);
            src += step;
        }

        // ---- S^T = K Q^T for both q-fragments; exp2 + pack in registers ----
        unsigned pa[8], pb[8];           // [mf*2 + half], packed bf16 P
        #pragma unroll
        for (int mf = 0; mf < 4; ++mf) {
            const int row = mf * 16 + l15;
            const int sw = row & 7;
            bf16x8 kh0 = *(const bf16x8*)(Ksh + row * 64 + ((quad ^ sw) * 8));
            bf16x8 kh1 = *(const bf16x8*)(Ksh + row * 64 + (((4 + quad) ^ sw) * 8));
            f32x4 cA = {}, cB = {};
            cA = __builtin_amdgcn_mfma_f32_16x16x32_bf16(kh0, qA[0], cA, 0, 0, 0);
            cA = __builtin_amdgcn_mfma_f32_16x16x32_bf16(kh1, qA[1], cA, 0, 0, 0);
            cB = __builtin_amdgcn_mfma_f32_16x16x32_bf16(kh0, qB[0], cB, 0, 0, 0);
            cB = __builtin_amdgcn_mfma_f32_16x16x32_bf16(kh1, qB[1], cB, 0, 0, 0);

            unsigned uA[4], uB[4];
            #pragma unroll
            for (int r = 0; r < 4; ++r) {
                union { float f; unsigned u; } p;
                p.f = __builtin_amdgcn_exp2f(cA[r]);
                uA[r] = p.u;
                p.f = __builtin_amdgcn_exp2f(cB[r]);
                uB[r] = p.u;
            }
            pa[mf * 2]     = __builtin_amdgcn_perm(uA[1], uA[0], 0x07060302u);
            pa[mf * 2 + 1] = __builtin_amdgcn_perm(uA[3], uA[2], 0x07060302u);
            pb[mf * 2]     = __builtin_amdgcn_perm(uB[1], uB[0], 0x07060302u);
            pb[mf * 2 + 1] = __builtin_amdgcn_perm(uB[3], uB[2], 0x07060302u);
        }

        // ---- in-register quad transpose: S^T frag -> PV A-operand frag ----
        pl32swap(pa[0], pa[2]); pl32swap(pa[1], pa[3]);
        pl32swap(pa[4], pa[6]); pl32swap(pa[5], pa[7]);
        pl16swap(pa[0], pa[2]); pl16swap(pa[1], pa[3]);
        pl16swap(pa[4], pa[6]); pl16swap(pa[5], pa[7]);
        pl32swap(pb[0], pb[2]); pl32swap(pb[1], pb[3]);
        pl32swap(pb[4], pb[6]); pl32swap(pb[5], pb[7]);
        pl16swap(pb[0], pb[2]); pl16swap(pb[1], pb[3]);
        pl16swap(pb[4], pb[6]); pl16swap(pb[5], pb[7]);
        bf16x8 pA0 = mk8(pa[0], pa[1], pa[2], pa[3]);
        bf16x8 pA1 = mk8(pa[4], pa[5], pa[6], pa[7]);
        bf16x8 pB0 = mk8(pb[0], pb[1], pb[2], pb[3]);
        bf16x8 pB1 = mk8(pb[4], pb[5], pb[6], pb[7]);

        // ---- l accumulation ----
        lAv = __builtin_amdgcn_mfma_f32_16x16x32_bf16(pA0, ones, lAv, 0, 0, 0);
        lAv = __builtin_amdgcn_mfma_f32_16x16x32_bf16(pA1, ones, lAv, 0, 0, 0);
        lBv = __builtin_amdgcn_mfma_f32_16x16x32_bf16(pB0, ones, lBv, 0, 0, 0);
        lBv = __builtin_amdgcn_mfma_f32_16x16x32_bf16(pB1, ones, lBv, 0, 0, 0);

        // ---- merged PV: V frags read once, feed both q-fragments ----
        #pragma unroll
        for (int nf = 0; nf < 4; ++nf) {
            const int row = nf * 16 + l15;
            const int sw = row & 7;
            bf16x8 vh0 = *(const bf16x8*)(Vsh + row * 64 + ((quad ^ sw) * 8));
            bf16x8 vh1 = *(const bf16x8*)(Vsh + row * 64 + (((4 + quad) ^ sw) * 8));
            f32x4 cA = oA[nf], cB = oB[nf];
            cA = __builtin_amdgcn_mfma_f32_16x16x32_bf16(pA0, vh0, cA, 0, 0, 0);
            cA = __builtin_amdgcn_mfma_f32_16x16x32_bf16(pA1, vh1, cA, 0, 0, 0);
            cB = __builtin_amdgcn_mfma_f32_16x16x32_bf16(pB0, vh0, cB, 0, 0, 0);
            cB = __builtin_amdgcn_mfma_f32_16x16x32_bf16(pB1, vh1, cB, 0, 0, 0);
            oA[nf] = cA;
            oB[nf] = cB;
        }
    }

    // ---- epilogue: normalized bf16 O directly (no partials, no combine) ----
    const int b = bh >> 4, hh = bh & 15;
    f32x4 rA, rB;
    #pragma unroll
    for (int r = 0; r < 4; ++r) {
        rA[r] = 1.0f / lAv[r];
        rB[r] = 1.0f / lBv[r];
    }
    #pragma unroll
    for (int nf = 0; nf < 4; ++nf) {
        #pragma unroll
        for (int r = 0; r < 4; ++r) {
            const int qa = q0 + quad * 4 + r;
            const int d = nf * 16 + l15;
            aoh[(size_t)(b * SEQ + qa) * DMODEL + hh * DHEAD + d] = f2bf(oA[nf][r] * rA[r]);
            aoh[(size_t)(b * SEQ + qa + 16) * DMODEL + hh * DHEAD + d] = f2bf(oB[nf][r] * rB[r]);
        }
    }
}

// ---------------- launch ----------------
extern "C" void kernel_launch(void* const* d_in, const int* in_sizes, int n_in,
                              void* d_out, int out_size, void* d_ws, size_t ws_size,
                              hipStream_t stream) {
    const float* x  = (const float*)d_in[0];
    // d_in[1] = pH : softmax shift-invariant, ignored
    const float* Wq = (const float*)d_in[2];
    const float* bq = (const float*)d_in[3];
    const float* Wk = (const float*)d_in[4];
    const float* bk = (const float*)d_in[5];
    const float* Wv = (const float*)d_in[6];
    const float* bv = (const float*)d_in[7];
    const float* Wo = (const float*)d_in[8];
    const float* bo = (const float*)d_in[9];
    float* out = (float*)d_out;

    char* ws = (char*)d_ws;
    const size_t MB = 1024 * 1024;
    short* qh  = (short*)(ws + 0 * MB);      // 8 MB
    short* kh  = (short*)(ws + 16 * MB);     // 8 MB
    short* vth = (short*)(ws + 32 * MB);     // 8 MB
    short* aoh = (short*)(ws + 48 * MB);     // 8 MB (written by attn, read by ogemm)
    short* xhi = (short*)(ws + 64 * MB);     // 8 MB (dead after QKV GEMM)
    short* wqkv_hi = (short*)(ws + 80 * MB); // 6 MB (dead after QKV GEMM)
    short* wto_hi  = (short*)(ws + 92 * MB); // 2 MB

    dim3 blk(256);

    hipLaunchKernelGGL(prep, dim3(2048 + 1024), blk, 0, stream,
                       x, xhi, Wq, Wk, Wv, Wo, wqkv_hi, wto_hi);

    const float qscale = 0.125f * 1.44269504088896f;   // fold 1/sqrt(dh)*log2(e)
    hipLaunchKernelGGL(qkv_gemm, dim3(3072 / 128, MROWS / 128), blk, 0, stream,
                       xhi, wqkv_hi, bq, bk, bv, qh, kh, vth, qscale);

    hipLaunchKernelGGL(attn_mfma, dim3(BATCH * NHEADS * (SEQ / 256)), dim3(512), 0, stream,
                       qh, kh, vth, aoh);

    hipLaunchKernelGGL(ogemm, dim3(1024 / 64, MROWS / 64), blk, 0, stream,
                       aoh, wto_hi, bo, out);
}

// Round 14
// 177.905 us; speedup vs baseline: 1.0159x; 1.0159x over previous
//
#include <hip/hip_runtime.h>
#include <hip/hip_bf16.h>
#include <math.h>

// Problem constants
#define BATCH 2
#define SEQ   2048
#define DMODEL 1024
#define NHEADS 16
#define DHEAD 64
#define MROWS (BATCH*SEQ)   // 4096

typedef __attribute__((ext_vector_type(8))) short bf16x8;
typedef __attribute__((ext_vector_type(4))) short bf16x4;
typedef __attribute__((ext_vector_type(4))) float f32x4;

__device__ __forceinline__ short f2bf(float f) {   // RNE float->bf16
    union { float f; unsigned u; } c; c.f = f;
    unsigned r = (c.u + 0x7fffu + ((c.u >> 16) & 1u)) >> 16;
    return (short)r;
}
__device__ __forceinline__ float bf2f(short h) {
    union { unsigned u; float f; } c; c.u = ((unsigned)(unsigned short)h) << 16;
    return c.f;
}

__device__ __forceinline__ void async_ld16(const void* g, void* l) {
    __builtin_amdgcn_global_load_lds(
        (const __attribute__((address_space(1))) unsigned*)g,
        (__attribute__((address_space(3))) unsigned*)l, 16, 0, 0);
}

// gfx950 cross-lane pair swaps (both outputs usable; in-place on 2 VGPRs)
__device__ __forceinline__ void pl32swap(unsigned &a, unsigned &b) {
    asm("v_permlane32_swap_b32 %0, %1" : "+v"(a), "+v"(b));
}
__device__ __forceinline__ void pl16swap(unsigned &a, unsigned &b) {
    asm("v_permlane16_swap_b32 %0, %1" : "+v"(a), "+v"(b));
}
__device__ __forceinline__ bf16x8 mk8(unsigned a, unsigned b, unsigned c, unsigned d) {
    union { unsigned u[4]; bf16x8 h; } t;
    t.u[0] = a; t.u[1] = b; t.u[2] = c; t.u[3] = d; return t.h;
}

// ---------------- fused prep: convert x -> bf16 AND transpose 4 weights ----------------
__global__ __launch_bounds__(256) void prep(
    const float* __restrict__ x, short* __restrict__ xhi,
    const float* __restrict__ W0, const float* __restrict__ W1,
    const float* __restrict__ W2, const float* __restrict__ W3,
    short* __restrict__ oqkv, short* __restrict__ oo)
{
    __shared__ float T[64][65];
    const int tid = threadIdx.x;
    if (blockIdx.x < 2048) {
        const int i = blockIdx.x * 256 + tid;
        const float4* p = (const float4*)x + (size_t)i * 2;
        float4 a = p[0], b = p[1];
        float v[8] = {a.x, a.y, a.z, a.w, b.x, b.y, b.z, b.w};
        bf16x8 H;
        #pragma unroll
        for (int j = 0; j < 8; ++j) H[j] = f2bf(v[j]);
        *((bf16x8*)xhi + i) = H;
        return;
    }
    const int bi = blockIdx.x - 2048;
    const int z = bi >> 8;
    const int t = bi & 255;
    const float* W = (z == 0) ? W0 : (z == 1) ? W1 : (z == 2) ? W2 : W3;
    short* out = (z < 3) ? (oqkv + (size_t)z * 1024 * 1024) : oo;
    const int n0 = (t & 15) * 64, k0 = (t >> 4) * 64;
    #pragma unroll
    for (int i = 0; i < 16; ++i) {
        const int idx = tid + i * 256;
        const int r = idx >> 6, c = idx & 63;
        T[r][c] = W[(size_t)(k0 + r) * DMODEL + n0 + c];
    }
    __syncthreads();
    #pragma unroll
    for (int i = 0; i < 4; ++i) {
        const int idx = tid + i * 256;
        const int r = idx >> 4, g = idx & 15;
        bf16x4 H;
        #pragma unroll
        for (int j = 0; j < 4; ++j)
            H[j] = f2bf(T[g * 4 + j][r]);
        *(bf16x4*)(out + (size_t)(n0 + r) * DMODEL + k0 + g * 4) = H;
    }
}

// ---------------- QKV GEMM v3: 128x128 tile + XCD swizzle, 768 blocks (3/CU) ----------------
__global__ __launch_bounds__(256, 3) void qkv_gemm(
    const short* __restrict__ Ahi, const short* __restrict__ Bthi,
    const float* __restrict__ b0, const float* __restrict__ b1, const float* __restrict__ b2,
    short* __restrict__ oqh, short* __restrict__ okh, short* __restrict__ ovh,
    float qscale)
{
    __shared__ short Ah[128 * 64], Bh[128 * 64];   // 16 KB + 16 KB

    const int tid  = threadIdx.x;
    const int lane = tid & 63;
    const int w    = tid >> 6;
    const int quad = lane >> 4;
    const int l15  = lane & 15;
    const int wr   = w >> 1, wc = w & 1;
    // XCD-aware swizzle: dispatch id -> contiguous logical chunk per XCD
    const int bid = blockIdx.y * 24 + blockIdx.x;      // 768 blocks
    const int swz = (bid & 7) * 96 + (bid >> 3);       // bijective (768%8==0)
    const int m0   = (swz / 24) * 128;
    const int n0   = (swz % 24) * 128;
    const int K    = DMODEL;

    f32x4 acc[4][4] = {};

    for (int k0 = 0; k0 < K; k0 += 64) {
        __syncthreads();
        // 2048 chunks (A:1024, B:1024); 8 wave-uniform calls/thread
        #pragma unroll
        for (int j = 0; j < 8; ++j) {
            const int base = w * 512 + j * 64;   // waves 0-1 -> A, 2-3 -> B (uniform)
            const int c = base + lane;
            if (base < 1024) {
                const int row = c >> 3, pos = (c & 7) ^ (row & 7);
                async_ld16(Ahi + (size_t)(m0 + row) * K + k0 + pos * 8, Ah + base * 8);
            } else {
                const int cb = c - 1024;
                const int row = cb >> 3, pos = (cb & 7) ^ (row & 7);
                async_ld16(Bthi + (size_t)(n0 + row) * K + k0 + pos * 8, Bh + (base - 1024) * 8);
            }
        }
        __syncthreads();

        #pragma unroll
        for (int s = 0; s < 2; ++s) {
            bf16x8 afh[4], bfh[4];
            #pragma unroll
            for (int mi = 0; mi < 4; ++mi) {
                const int row = wr * 64 + mi * 16 + l15;
                const int pos = (s * 4 + quad) ^ (row & 7);
                afh[mi] = *(const bf16x8*)(Ah + row * 64 + pos * 8);
            }
            #pragma unroll
            for (int ni = 0; ni < 4; ++ni) {
                const int row = wc * 64 + ni * 16 + l15;
                const int pos = (s * 4 + quad) ^ (row & 7);
                bfh[ni] = *(const bf16x8*)(Bh + row * 64 + pos * 8);
            }
            #pragma unroll
            for (int mi = 0; mi < 4; ++mi)
                #pragma unroll
                for (int ni = 0; ni < 4; ++ni)
                    acc[mi][ni] = __builtin_amdgcn_mfma_f32_16x16x32_bf16(
                        afh[mi], bfh[ni], acc[mi][ni], 0, 0, 0);
        }
    }

    const int nbase = n0 + wc * 64;              // one head per wave
    const int which = nbase >> 10;               // 0=q, 1=k, 2=v (wave-uniform)
    const int hh = (nbase & 1023) >> 6;
    const int mb = m0 + wr * 64;
    const int b = mb >> 11, sbase = mb & (SEQ - 1);
    __syncthreads();   // all waves done reading Ah/Bh; reuse as scratch
    short* scr = (w < 2) ? (Ah + w * 4096) : (Bh + (w - 2) * 4096);  // 8 KB/wave

    if (which < 2) {
        const float* bias = which ? b1 : b0;
        short* dstp = which ? okh : oqh;
        const float scl = which ? 1.0f : qscale;
        #pragma unroll
        for (int mi = 0; mi < 4; ++mi)
            #pragma unroll
            for (int ni = 0; ni < 4; ++ni)
                #pragma unroll
                for (int r = 0; r < 4; ++r) {
                    const int sloc = mi * 16 + quad * 4 + r;
                    const int dloc = ni * 16 + l15;
                    const int nn = (nbase + ni * 16 + l15) & 1023;
                    scr[sloc * 64 + (((dloc >> 3) ^ (sloc & 7)) * 8) + (dloc & 7)] =
                        f2bf((acc[mi][ni][r] + bias[nn]) * scl);
                }
        #pragma unroll
        for (int i = 0; i < 8; ++i) {
            const int sloc = i * 8 + (lane >> 3);
            const int cph = (lane & 7) ^ (sloc & 7);
            bf16x8 row = *(const bf16x8*)(scr + sloc * 64 + cph * 8);
            const int dloc = (lane & 7) * 8;
            *(bf16x8*)(dstp + ((size_t)(b * NHEADS + hh) * SEQ + sbase + sloc) * DHEAD + dloc) = row;
        }
    } else {
        #pragma unroll
        for (int mi = 0; mi < 4; ++mi)
            #pragma unroll
            for (int ni = 0; ni < 4; ++ni)
                #pragma unroll
                for (int r = 0; r < 4; ++r) {
                    const int sloc = mi * 16 + quad * 4 + r;
                    const int dloc = ni * 16 + l15;
                    const int nn = (nbase + ni * 16 + l15) & 1023;
                    scr[dloc * 64 + (((sloc >> 3) ^ (dloc & 7)) * 8) + (sloc & 7)] =
                        f2bf(acc[mi][ni][r] + b2[nn]);
                }
        #pragma unroll
        for (int i = 0; i < 8; ++i) {
            const int dloc = i * 8 + (lane >> 3);
            const int cph = (lane & 7) ^ (dloc & 7);
            bf16x8 row = *(const bf16x8*)(scr + dloc * 64 + cph * 8);
            const int sg = sbase + (lane & 7) * 8;
            *(bf16x8*)(ovh + ((size_t)(b * NHEADS + hh) * DHEAD + dloc) * SEQ + sg) = row;
        }
    }
}

// ---------------- O-proj GEMM v3 (RESTORED R12): 64x128 tile + XCD swizzle, 512 blocks ----------------
// R13 falsified the 64x64@4/CU revert (180.7 vs 178.3): the 64x128 @ 2/CU
// structure is ogemm's best measured form. Restored byte-identical to R12.
__global__ __launch_bounds__(256) void ogemm(
    const short* __restrict__ Ahi, const short* __restrict__ Bthi,
    const float* __restrict__ b0, float* __restrict__ outf)
{
    __shared__ short Ah[64 * 64], Bh[128 * 64];   // 8 KB + 16 KB

    const int tid  = threadIdx.x;
    const int lane = tid & 63;
    const int w    = tid >> 6;
    const int quad = lane >> 4;
    const int l15  = lane & 15;
    const int wr   = w >> 1, wc = w & 1;
    const int bid = blockIdx.y * 8 + blockIdx.x;       // 512 blocks
    const int swz = (bid & 7) * 64 + (bid >> 3);       // bijective (512%8==0)
    const int m0   = (swz / 8) * 64;
    const int n0   = (swz % 8) * 128;
    const int K    = DMODEL;

    f32x4 acc[2][4] = {};

    for (int k0 = 0; k0 < K; k0 += 64) {
        __syncthreads();
        #pragma unroll
        for (int j = 0; j < 6; ++j) {
            const int base = w * 384 + j * 64;   // A/B split at 512 (wave-uniform)
            const int c = base + lane;
            if (base < 512) {
                const int row = c >> 3, pos = (c & 7) ^ (row & 7);
                async_ld16(Ahi + (size_t)(m0 + row) * K + k0 + pos * 8, Ah + base * 8);
            } else {
                const int cb = c - 512;
                const int row = cb >> 3, pos = (cb & 7) ^ (row & 7);
                async_ld16(Bthi + (size_t)(n0 + row) * K + k0 + pos * 8, Bh + (base - 512) * 8);
            }
        }
        __syncthreads();

        #pragma unroll
        for (int s = 0; s < 2; ++s) {
            bf16x8 afh[2], bfh[4];
            #pragma unroll
            for (int mi = 0; mi < 2; ++mi) {
                const int row = wr * 32 + mi * 16 + l15;
                const int pos = (s * 4 + quad) ^ (row & 7);
                afh[mi] = *(const bf16x8*)(Ah + row * 64 + pos * 8);
            }
            #pragma unroll
            for (int ni = 0; ni < 4; ++ni) {
                const int row = wc * 64 + ni * 16 + l15;
                const int pos = (s * 4 + quad) ^ (row & 7);
                bfh[ni] = *(const bf16x8*)(Bh + row * 64 + pos * 8);
            }
            #pragma unroll
            for (int mi = 0; mi < 2; ++mi)
                #pragma unroll
                for (int ni = 0; ni < 4; ++ni)
                    acc[mi][ni] = __builtin_amdgcn_mfma_f32_16x16x32_bf16(
                        afh[mi], bfh[ni], acc[mi][ni], 0, 0, 0);
        }
    }

    #pragma unroll
    for (int mi = 0; mi < 2; ++mi)
        #pragma unroll
        for (int ni = 0; ni < 4; ++ni)
            #pragma unroll
            for (int r = 0; r < 4; ++r) {
                const int m = m0 + wr * 32 + mi * 16 + quad * 4 + r;
                const int nn = n0 + wc * 64 + ni * 16 + l15;
                outf[(size_t)m * DMODEL + nn] = acc[mi][ni][r] + b0[nn];
            }
}

// ---------------- MFMA flash attention v19 (FROZEN): 8-wave, two-barrier loop, sk=1 ----------------
__global__ __launch_bounds__(512) void attn_mfma(
    const short* __restrict__ Qh_g, const short* __restrict__ Kh_g,
    const short* __restrict__ Vth_g,
    short* __restrict__ aoh)
{
    __shared__ short Ksh[4096];          // [key][d] swizzled, 8 KB
    __shared__ short Vsh[4096];          // [d][s] swizzled, 8 KB

    const int tid  = threadIdx.x;
    const int lane = tid & 63;
    const int w    = tid >> 6;           // 0..7
    const int quad = lane >> 4;
    const int l15  = lane & 15;

    const int bh    = blockIdx.x & 31;        // XCD-local head
    const int qtile = blockIdx.x >> 5;        // 0..7
    const int q0    = qtile * 256 + w * 32;
    const size_t kvb = (size_t)bh * SEQ * DHEAD;

    bf16x8 ones;
    #pragma unroll
    for (int j = 0; j < 8; ++j) ones[j] = (short)0x3f80;   // bf16 1.0

    bf16x8 qA[2], qB[2];
    {
        const size_t qrA = kvb + (size_t)(q0 + l15) * DHEAD;
        const size_t qrB = kvb + (size_t)(q0 + 16 + l15) * DHEAD;
        qA[0] = *(const bf16x8*)(Qh_g + qrA + quad * 8);
        qA[1] = *(const bf16x8*)(Qh_g + qrA + 32 + quad * 8);
        qB[0] = *(const bf16x8*)(Qh_g + qrB + quad * 8);
        qB[1] = *(const bf16x8*)(Qh_g + qrB + 32 + quad * 8);
    }

    const bool stager = (w < 4);
    const bool isv = (w >= 2) && stager;
    short* dst = isv ? Vsh : Ksh;
    // per-j pre-swizzled global offsets + linear LDS write addresses (stagers only)
    int goff[4]; short* ldst[4];
    #pragma unroll
    for (int j = 0; j < 4; ++j) {
        const int c = (w & 1) * 256 + j * 64 + lane;
        const int row = c >> 3, pos = (c & 7) ^ (row & 7);
        goff[j] = isv ? (row * SEQ + pos * 8) : (row * DHEAD + pos * 8);
        ldst[j] = dst + (size_t)c * 8;
    }

    const int kb1 = SEQ;                                   // 32 iters of 64 keys
    const int step = isv ? 64 : 64 * DHEAD;
    const short* src = isv ? (Vth_g + kvb) : (Kh_g + kvb);

    f32x4 oA[4] = {}, oB[4] = {};
    f32x4 lAv = {}, lBv = {};

    // prologue: stagers load first tile into registers
    bf16x8 stg[4];
    if (stager) {
        #pragma unroll
        for (int j = 0; j < 4; ++j) stg[j] = *(const bf16x8*)(src + goff[j]);
        src += step;
    }

    for (int kb = 0; kb < kb1; kb += 64) {
        __syncthreads();                 // A: all waves done reading prev tile
        if (stager) {
            #pragma unroll
            for (int j = 0; j < 4; ++j) *(bf16x8*)ldst[j] = stg[j];
        }
        __syncthreads();                 // B: writes visible to all waves
        if (stager && kb + 64 < kb1) {   // prefetch next tile; flies under compute
            #pragma unroll
            for (int j = 0; j < 4; ++j) stg[j] = *(const bf16x8*)(src + goff[j]);
            src += step;
        }

        // ---- S^T = K Q^T for both q-fragments; exp2 + pack in registers ----
        unsigned pa[8], pb[8];           // [mf*2 + half], packed bf16 P
        #pragma unroll
        for (int mf = 0; mf < 4; ++mf) {
            const int row = mf * 16 + l15;
            const int sw = row & 7;
            bf16x8 kh0 = *(const bf16x8*)(Ksh + row * 64 + ((quad ^ sw) * 8));
            bf16x8 kh1 = *(const bf16x8*)(Ksh + row * 64 + (((4 + quad) ^ sw) * 8));
            f32x4 cA = {}, cB = {};
            cA = __builtin_amdgcn_mfma_f32_16x16x32_bf16(kh0, qA[0], cA, 0, 0, 0);
            cA = __builtin_amdgcn_mfma_f32_16x16x32_bf16(kh1, qA[1], cA, 0, 0, 0);
            cB = __builtin_amdgcn_mfma_f32_16x16x32_bf16(kh0, qB[0], cB, 0, 0, 0);
            cB = __builtin_amdgcn_mfma_f32_16x16x32_bf16(kh1, qB[1], cB, 0, 0, 0);

            unsigned uA[4], uB[4];
            #pragma unroll
            for (int r = 0; r < 4; ++r) {
                union { float f; unsigned u; } p;
                p.f = __builtin_amdgcn_exp2f(cA[r]);
                uA[r] = p.u;
                p.f = __builtin_amdgcn_exp2f(cB[r]);
                uB[r] = p.u;
            }
            pa[mf * 2]     = __builtin_amdgcn_perm(uA[1], uA[0], 0x07060302u);
            pa[mf * 2 + 1] = __builtin_amdgcn_perm(uA[3], uA[2], 0x07060302u);
            pb[mf * 2]     = __builtin_amdgcn_perm(uB[1], uB[0], 0x07060302u);
            pb[mf * 2 + 1] = __builtin_amdgcn_perm(uB[3], uB[2], 0x07060302u);
        }

        // ---- in-register quad transpose: S^T frag -> PV A-operand frag ----
        pl32swap(pa[0], pa[2]); pl32swap(pa[1], pa[3]);
        pl32swap(pa[4], pa[6]); pl32swap(pa[5], pa[7]);
        pl16swap(pa[0], pa[2]); pl16swap(pa[1], pa[3]);
        pl16swap(pa[4], pa[6]); pl16swap(pa[5], pa[7]);
        pl32swap(pb[0], pb[2]); pl32swap(pb[1], pb[3]);
        pl32swap(pb[4], pb[6]); pl32swap(pb[5], pb[7]);
        pl16swap(pb[0], pb[2]); pl16swap(pb[1], pb[3]);
        pl16swap(pb[4], pb[6]); pl16swap(pb[5], pb[7]);
        bf16x8 pA0 = mk8(pa[0], pa[1], pa[2], pa[3]);
        bf16x8 pA1 = mk8(pa[4], pa[5], pa[6], pa[7]);
        bf16x8 pB0 = mk8(pb[0], pb[1], pb[2], pb[3]);
        bf16x8 pB1 = mk8(pb[4], pb[5], pb[6], pb[7]);

        // ---- l accumulation ----
        lAv = __builtin_amdgcn_mfma_f32_16x16x32_bf16(pA0, ones, lAv, 0, 0, 0);
        lAv = __builtin_amdgcn_mfma_f32_16x16x32_bf16(pA1, ones, lAv, 0, 0, 0);
        lBv = __builtin_amdgcn_mfma_f32_16x16x32_bf16(pB0, ones, lBv, 0, 0, 0);
        lBv = __builtin_amdgcn_mfma_f32_16x16x32_bf16(pB1, ones, lBv, 0, 0, 0);

        // ---- merged PV: V frags read once, feed both q-fragments ----
        #pragma unroll
        for (int nf = 0; nf < 4; ++nf) {
            const int row = nf * 16 + l15;
            const int sw = row & 7;
            bf16x8 vh0 = *(const bf16x8*)(Vsh + row * 64 + ((quad ^ sw) * 8));
            bf16x8 vh1 = *(const bf16x8*)(Vsh + row * 64 + (((4 + quad) ^ sw) * 8));
            f32x4 cA = oA[nf], cB = oB[nf];
            cA = __builtin_amdgcn_mfma_f32_16x16x32_bf16(pA0, vh0, cA, 0, 0, 0);
            cA = __builtin_amdgcn_mfma_f32_16x16x32_bf16(pA1, vh1, cA, 0, 0, 0);
            cB = __builtin_amdgcn_mfma_f32_16x16x32_bf16(pB0, vh0, cB, 0, 0, 0);
            cB = __builtin_amdgcn_mfma_f32_16x16x32_bf16(pB1, vh1, cB, 0, 0, 0);
            oA[nf] = cA;
            oB[nf] = cB;
        }
    }

    // ---- epilogue: normalized bf16 O directly (no partials, no combine) ----
    const int b = bh >> 4, hh = bh & 15;
    f32x4 rA, rB;
    #pragma unroll
    for (int r = 0; r < 4; ++r) {
        rA[r] = 1.0f / lAv[r];
        rB[r] = 1.0f / lBv[r];
    }
    #pragma unroll
    for (int nf = 0; nf < 4; ++nf) {
        #pragma unroll
        for (int r = 0; r < 4; ++r) {
            const int qa = q0 + quad * 4 + r;
            const int d = nf * 16 + l15;
            aoh[(size_t)(b * SEQ + qa) * DMODEL + hh * DHEAD + d] = f2bf(oA[nf][r] * rA[r]);
            aoh[(size_t)(b * SEQ + qa + 16) * DMODEL + hh * DHEAD + d] = f2bf(oB[nf][r] * rB[r]);
        }
    }
}

// ---------------- launch ----------------
extern "C" void kernel_launch(void* const* d_in, const int* in_sizes, int n_in,
                              void* d_out, int out_size, void* d_ws, size_t ws_size,
                              hipStream_t stream) {
    const float* x  = (const float*)d_in[0];
    // d_in[1] = pH : softmax shift-invariant, ignored
    const float* Wq = (const float*)d_in[2];
    const float* bq = (const float*)d_in[3];
    const float* Wk = (const float*)d_in[4];
    const float* bk = (const float*)d_in[5];
    const float* Wv = (const float*)d_in[6];
    const float* bv = (const float*)d_in[7];
    const float* Wo = (const float*)d_in[8];
    const float* bo = (const float*)d_in[9];
    float* out = (float*)d_out;

    char* ws = (char*)d_ws;
    const size_t MB = 1024 * 1024;
    short* qh  = (short*)(ws + 0 * MB);      // 8 MB
    short* kh  = (short*)(ws + 16 * MB);     // 8 MB
    short* vth = (short*)(ws + 32 * MB);     // 8 MB
    short* aoh = (short*)(ws + 48 * MB);     // 8 MB (written by attn, read by ogemm)
    short* xhi = (short*)(ws + 64 * MB);     // 8 MB (dead after QKV GEMM)
    short* wqkv_hi = (short*)(ws + 80 * MB); // 6 MB (dead after QKV GEMM)
    short* wto_hi  = (short*)(ws + 92 * MB); // 2 MB

    dim3 blk(256);

    hipLaunchKernelGGL(prep, dim3(2048 + 1024), blk, 0, stream,
                       x, xhi, Wq, Wk, Wv, Wo, wqkv_hi, wto_hi);

    const float qscale = 0.125f * 1.44269504088896f;   // fold 1/sqrt(dh)*log2(e)
    hipLaunchKernelGGL(qkv_gemm, dim3(3072 / 128, MROWS / 128), blk, 0, stream,
                       xhi, wqkv_hi, bq, bk, bv, qh, kh, vth, qscale);

    hipLaunchKernelGGL(attn_mfma, dim3(BATCH * NHEADS * (SEQ / 256)), dim3(512), 0, stream,
                       qh, kh, vth, aoh);

    hipLaunchKernelGGL(ogemm, dim3(1024 / 128, MROWS / 64), blk, 0, stream,
                       aoh, wto_hi, bo, out);
}